// Round 3
// baseline (92.963 us; speedup 1.0000x reference)
//
#include <hip/hip_runtime.h>
#include <math.h>

#define NCLS 81
#define A_ANCH 8732
#define B_BATCH 64
#define EPSF 1e-7f
#define TA 64
#define NB ((A_ANCH + TA - 1) / TA)   // 137 blocks per batch (136 full + tail of 28)

// ---------------- workspace layout ----------------
// [0]          neg_ce  : B*A floats
// [NEG_BYTES]  pos_loss: B floats
// [+256]       loc_loss: B floats
// [+512]       nm      : B ints
// [+768]       accum   : 2 doubles
// [+784]       hits    : 1 ull
static const size_t NEG_BYTES = (size_t)B_BATCH * A_ANCH * sizeof(float);

#define GLOAD_LDS16(g, l) __builtin_amdgcn_global_load_lds( \
    (const __attribute__((address_space(1))) void*)(g),      \
    (__attribute__((address_space(3))) void*)(l), 16, 0, 0)
#define GLOAD_LDS4(g, l) __builtin_amdgcn_global_load_lds(  \
    (const __attribute__((address_space(1))) void*)(g),      \
    (__attribute__((address_space(3))) void*)(l), 4, 0, 0)

// ---------------- K1: per-anchor logsumexp + CE + GIoU ----------------
// One wave per block, one thread per anchor, 64-anchor tile staged in LDS.
// 20.7 KB LDS -> 7 blocks/CU: 7 independent stage/compute pipelines per CU.
__global__ __launch_bounds__(TA) void anchor_kernel(
    const float* __restrict__ conf, const float* __restrict__ loc,
    const float* __restrict__ tgt, float* __restrict__ neg_ce,
    float* __restrict__ pos_loss, float* __restrict__ loc_loss, int* __restrict__ nm)
{
    __shared__ float sconf[TA * NCLS];   // 20,736 B

    int b   = blockIdx.x / NB;
    int blk = blockIdx.x % NB;
    int tid = threadIdx.x;               // == lane (single wave)
    int rows = A_ANCH - blk * TA; if (rows > TA) rows = TA;
    const float* gsrc = conf + ((size_t)b * A_ANCH + (size_t)blk * TA) * NCLS;

    if (rows == TA) {
        // 64*81 = 5184 dwords = 20 chunks of 256 dwords (width-16) + 64 dwords (width-4)
        #pragma unroll
        for (int c = 0; c < 20; ++c) {
            GLOAD_LDS16(gsrc + c * 256 + tid * 4, sconf + c * 256);
        }
        GLOAD_LDS4(gsrc + 5120 + tid, sconf + 5120);
    } else {
        int n = rows * NCLS;
        for (int i = tid; i < n; i += TA) sconf[i] = gsrc[i];
    }

    // label load overlaps the staging (no LDS dependence)
    size_t ridx = (size_t)b * A_ANCH + (size_t)blk * TA + tid;
    int label = 0;
    if (tid < rows) label = (int)tgt[ridx * 5 + 4];

    __syncthreads();   // drains vmcnt (gload_lds) before LDS reads

    if (tid < rows) {
        const float* r = sconf + tid * NCLS;   // lane stride 81 dwords: 2-way alias = free
        float s0 = 0.f, s1 = 0.f, s2 = 0.f, s3 = 0.f;
        #pragma unroll
        for (int j = 0; j < 80; j += 4) {
            s0 += __expf(r[j]);
            s1 += __expf(r[j + 1]);
            s2 += __expf(r[j + 2]);
            s3 += __expf(r[j + 3]);
        }
        float s   = (s0 + s1) + (s2 + s3) + __expf(r[80]);
        float lse = __logf(s);

        if (label > 0) {
            float ce = lse - r[label];
            const float* p = loc + ridx * 4;
            float px1 = p[0], py1 = p[1], px2 = p[2], py2 = p[3];
            const float* t = tgt + ridx * 5;
            float tx1 = t[0], ty1 = t[1], tx2 = t[2], ty2 = t[3];
            float area_p = (px2 - px1) * (py2 - py1);
            float area_t = (tx2 - tx1) * (ty2 - ty1);
            float iw = fmaxf(fminf(px2, tx2) - fmaxf(px1, tx1), 0.f);
            float ih = fmaxf(fminf(py2, ty2) - fmaxf(py1, ty1), 0.f);
            float inter = iw * ih;
            float uni   = area_p + area_t - inter;
            float iou   = inter / (uni + EPSF);
            float cw = fmaxf(px2, tx2) - fminf(px1, tx1);
            float ch = fmaxf(py2, ty2) - fminf(py1, ty1);
            float area_c = cw * ch;
            float giou = iou - (area_c - uni) / (area_c + EPSF);
            atomicAdd(&pos_loss[b], ce);
            atomicAdd(&loc_loss[b], 1.f - giou);
            neg_ce[ridx] = -1.f;
        } else {
            neg_ce[ridx] = lse - r[0];   // log(sum exp(x_j - x_0)) > 0 always
        }
    }

    // nm: one ballot + one atomic per block (~1.3 positives / 64 anchors)
    unsigned long long pm = __ballot(label > 0);
    if (tid == 0 && pm) atomicAdd(&nm[b], __popcll(pm));
}

// ---------------- K2: per-batch top-k sum (hard negative mining) ----------------
#define K2_T 1024
#define VPT 9   // ceil(8732/1024)

__global__ __launch_bounds__(K2_T) void topk_kernel(
    const float* __restrict__ neg_ce, const float* __restrict__ pos_loss,
    const float* __restrict__ loc_loss, const int* __restrict__ nm,
    double* __restrict__ accum, unsigned long long* __restrict__ hits)
{
    __shared__ int   cnt[36];   // one pre-zeroed slot per binary-search iteration
    __shared__ float fsum[4];
    int b = blockIdx.x, tid = threadIdx.x;
    int lane = tid & 63;
    if (tid < 36) cnt[tid] = 0;
    if (tid < 4)  fsum[tid] = 0.f;

    float v[VPT];
    #pragma unroll
    for (int i = 0; i < VPT; ++i) {
        int idx = tid + i * K2_T;
        v[i] = (idx < A_ANCH) ? neg_ce[(size_t)b * A_ANCH + idx] : -1.f;
    }

    // count & sum of all non-negative entries (pos anchors marked -1)
    int c = 0; float s = 0.f;
    #pragma unroll
    for (int i = 0; i < VPT; ++i) { if (v[i] >= 0.f) { c++; s += v[i]; } }
    for (int off = 32; off; off >>= 1) { c += __shfl_xor(c, off); s += __shfl_xor(s, off); }
    __syncthreads();
    if (lane == 0) { atomicAdd(&cnt[32], c); atomicAdd(&fsum[0], s); }
    __syncthreads();
    int c0 = cnt[32]; float sall = fsum[0];
    int k = 3 * nm[b];

    float negl = 0.f;
    if (k >= c0) {
        negl = sall;
    } else if (k > 0) {
        // binary search on IEEE bits for the k-th largest value (values > 0)
        unsigned lo = 0u, hi = 0x7F800000u;
        int it = 0;
        while (hi - lo > 1u) {            // 31 uniform iterations
            unsigned mid = lo + (hi - lo) / 2u;
            float thr = __uint_as_float(mid);
            int cc = 0;
            #pragma unroll
            for (int i = 0; i < VPT; ++i) cc += (v[i] >= thr) ? 1 : 0;
            for (int off = 32; off; off >>= 1) cc += __shfl_xor(cc, off);
            if (lane == 0) atomicAdd(&cnt[it], cc);
            __syncthreads();
            if (cnt[it] >= k) lo = mid; else hi = mid;
            ++it;
        }
        float t = __uint_as_float(lo);    // exact k-th largest value
        int cg = 0; float sg = 0.f;
        #pragma unroll
        for (int i = 0; i < VPT; ++i) { if (v[i] > t) { cg++; sg += v[i]; } }
        for (int off = 32; off; off >>= 1) { cg += __shfl_xor(cg, off); sg += __shfl_xor(sg, off); }
        if (lane == 0) { atomicAdd(&cnt[33], cg); atomicAdd(&fsum[1], sg); }
        __syncthreads();
        negl = fsum[1] + (float)(k - cnt[33]) * t;   // ties contribute value t
    }

    if (tid == 0) {
        atomicAdd(&accum[0], (double)(pos_loss[b] + negl));
        atomicAdd(&accum[1], (double)loc_loss[b]);
        atomicAdd(hits, (unsigned long long)nm[b]);
    }
}

// ---------------- K3: finalize ----------------
__global__ void finalize_kernel(const double* __restrict__ accum,
                                const unsigned long long* __restrict__ hits,
                                float* __restrict__ out) {
    if (threadIdx.x == 0 && blockIdx.x == 0) {
        double conf_s = accum[0], loc_s = accum[1];
        unsigned long long h = *hits;
        double denom = (double)(h > 0 ? h : 1ull);
        if (h > 0) {
            out[0] = (float)((conf_s + loc_s) / denom);
            out[1] = (float)(conf_s / denom);
            out[2] = (float)(loc_s / denom);
        } else {
            out[0] = 0.f; out[1] = 0.f; out[2] = 0.f;
        }
    }
}

extern "C" void kernel_launch(void* const* d_in, const int* in_sizes, int n_in,
                              void* d_out, int out_size, void* d_ws, size_t ws_size,
                              hipStream_t stream) {
    const float* conf = (const float*)d_in[0];
    const float* loc  = (const float*)d_in[1];
    const float* tgt  = (const float*)d_in[2];
    float* out = (float*)d_out;

    char* ws = (char*)d_ws;
    float* neg_ce   = (float*)ws;
    float* pos_loss = (float*)(ws + NEG_BYTES);
    float* loc_loss = (float*)(ws + NEG_BYTES + 256);
    int*   nm       = (int*)  (ws + NEG_BYTES + 512);
    double* accum   = (double*)(ws + NEG_BYTES + 768);
    unsigned long long* hits = (unsigned long long*)(ws + NEG_BYTES + 784);

    // zero the small accumulator region (graph-capturable async memset)
    hipMemsetAsync(ws + NEG_BYTES, 0, 1024, stream);

    anchor_kernel<<<dim3(B_BATCH * NB), dim3(TA), 0, stream>>>(
        conf, loc, tgt, neg_ce, pos_loss, loc_loss, nm);
    topk_kernel<<<dim3(B_BATCH), dim3(K2_T), 0, stream>>>(
        neg_ce, pos_loss, loc_loss, nm, accum, hits);
    finalize_kernel<<<1, 64, 0, stream>>>(accum, hits, out);
}